// Round 1
// baseline (1020.979 us; speedup 1.0000x reference)
//
#include <hip/hip_runtime.h>
#include <math.h>

// Problem constants (fixed by setup_inputs)
#define BATCH 8
#define WAY 5
#define NSHOT 1
#define NQ 75
#define NSAMP 80          // WAY*NSHOT + NQ
#define NP 9              // patches
#define CCH 640
#define HW 32
#define KSZ 8
#define KLEN 192          // 3*8*8
#define NPOS 16           // 4x4 conv output positions
#define NIMG (BATCH*NSAMP*NP)   // 5760
#define APAD 196          // 192 + 4 pad (break 32-bank stride)
#define SPAD 644          // 640 + 4 pad

// Kernel 1: per patch-image: strided conv (GEMM 16x640x192) + per-position
// L2-norm over channels + spatial mean + per-row L2-norm over channels.
// Output: featn [NIMG, 640], fully normalized rows.
__global__ __launch_bounds__(320) void conv_norm_pool(
    const float* __restrict__ x,     // [NIMG, 3, 32, 32]
    const float* __restrict__ w,     // [640, 192]  (OIHW flattened)
    float* __restrict__ featn)       // [NIMG, 640]
{
    __shared__ float A[NPOS][APAD];
    __shared__ float red[5][NPOS];
    __shared__ float inv_s[NPOS];
    __shared__ float redc[5];
    __shared__ float invc_s;

    const int n = blockIdx.x;
    const int t = threadIdx.x;
    const float* xp = x + (size_t)n * 3072;

    // Load + rearrange input patch into A[s][k], s=4*i+j, k=ci*64+kh*8+kw
    for (int e = t; e < 3072; e += 320) {
        int ci  = e >> 10;
        int rem = e & 1023;
        int h   = rem >> 5;
        int wc  = rem & 31;
        int s   = ((h >> 3) << 2) + (wc >> 3);
        int k   = ci * 64 + ((h & 7) << 3) + (wc & 7);
        A[s][k] = xp[e];
    }
    __syncthreads();

    const int c0 = t;
    const int c1 = t + 320;
    float acc0[NPOS], acc1[NPOS];
#pragma unroll
    for (int s = 0; s < NPOS; s++) { acc0[s] = 0.f; acc1[s] = 0.f; }

    const float4* w0p = (const float4*)(w + (size_t)c0 * KLEN);
    const float4* w1p = (const float4*)(w + (size_t)c1 * KLEN);
    for (int kk = 0; kk < KLEN / 4; kk++) {
        float4 w0 = w0p[kk];
        float4 w1 = w1p[kk];
#pragma unroll
        for (int s = 0; s < NPOS; s++) {
            float4 a = *(const float4*)&A[s][kk * 4];
            acc0[s] += a.x * w0.x + a.y * w0.y + a.z * w0.z + a.w * w0.w;
            acc1[s] += a.x * w1.x + a.y * w1.y + a.z * w1.z + a.w * w1.w;
        }
    }

    // Reduction 1: per-position sum of squares over all 640 channels
    float ssq[NPOS];
#pragma unroll
    for (int s = 0; s < NPOS; s++)
        ssq[s] = acc0[s] * acc0[s] + acc1[s] * acc1[s];
#pragma unroll
    for (int off = 32; off >= 1; off >>= 1) {
#pragma unroll
        for (int s = 0; s < NPOS; s++)
            ssq[s] += __shfl_down(ssq[s], off);
    }
    const int wv = t >> 6;
    const int lane = t & 63;
    if (lane == 0) {
#pragma unroll
        for (int s = 0; s < NPOS; s++) red[wv][s] = ssq[s];
    }
    __syncthreads();
    if (t < NPOS) {
        float v = red[0][t] + red[1][t] + red[2][t] + red[3][t] + red[4][t];
        inv_s[t] = 1.f / fmaxf(sqrtf(v), 1e-12f);
    }
    __syncthreads();

    // Pool: mean over positions of normalized vectors
    float pool0 = 0.f, pool1 = 0.f;
#pragma unroll
    for (int s = 0; s < NPOS; s++) {
        pool0 += acc0[s] * inv_s[s];
        pool1 += acc1[s] * inv_s[s];
    }
    pool0 *= (1.f / 16.f);
    pool1 *= (1.f / 16.f);

    // Reduction 2: row L2-norm over channels of pooled vector
    float sc = pool0 * pool0 + pool1 * pool1;
#pragma unroll
    for (int off = 32; off >= 1; off >>= 1) sc += __shfl_down(sc, off);
    if (lane == 0) redc[wv] = sc;
    __syncthreads();
    if (t == 0) {
        float v = redc[0] + redc[1] + redc[2] + redc[3] + redc[4];
        invc_s = 1.f / fmaxf(sqrtf(v), 1e-12f);
    }
    __syncthreads();
    const float ic = invc_s;
    featn[(size_t)n * CCH + c0] = pool0 * ic;
    featn[(size_t)n * CCH + c1] = pool1 * ic;
}

// Kernel 2: per (b, m, n): 9x9 similarity matrix + greedy row/col-deletion.
// out[b][n][m] = sum_i relu(max_i) * 0.5^i
__global__ __launch_bounds__(128) void sim_greedy(
    const float* __restrict__ featn,  // [NIMG, 640]
    float* __restrict__ out)          // [8, 75, 5]
{
    __shared__ float rows[18][SPAD];  // 0..8 support patches, 9..17 query patches
    __shared__ float sim_s[NP * NP];

    const int n = blockIdx.x;   // query 0..74
    const int m = blockIdx.y;   // support 0..4
    const int b = blockIdx.z;   // batch 0..7
    const int t = threadIdx.x;

    for (int r = 0; r < 18; r++) {
        int g = (r < NP) ? ((b * NSAMP + m) * NP + r)
                         : ((b * NSAMP + WAY + n) * NP + (r - NP));
        const float* src = featn + (size_t)g * CCH;
        for (int c = t; c < CCH; c += 128) rows[r][c] = src[c];
    }
    __syncthreads();

    if (t < NP * NP) {
        int h = t / NP;
        int wq = t - h * NP;
        const float* ph = rows[h];
        const float* pq = rows[NP + wq];
        float d = 0.f;
        for (int c = 0; c < CCH; c += 4) {
            float4 a  = *(const float4*)&ph[c];
            float4 b4 = *(const float4*)&pq[c];
            d += a.x * b4.x + a.y * b4.y + a.z * b4.z + a.w * b4.w;
        }
        sim_s[t] = d;
    }
    __syncthreads();

    if (t == 0) {
        float total = 0.f;
        float beta = 1.f;
        unsigned rm = 0x1FF, cm = 0x1FF;
        for (int it = 0; it < NP; it++) {
            float best = -1e30f;
            int bh = 0, bw = 0;
            for (int h = 0; h < NP; h++) {
                if (!((rm >> h) & 1)) continue;
                for (int wq = 0; wq < NP; wq++) {
                    if (!((cm >> wq) & 1)) continue;
                    float v = sim_s[h * NP + wq];
                    if (v > best) { best = v; bh = h; bw = wq; }
                }
            }
            total += fmaxf(best, 0.f) * beta;
            beta *= 0.5f;
            rm &= ~(1u << bh);
            cm &= ~(1u << bw);
        }
        out[((size_t)b * NQ + n) * WAY + m] = total;
    }
}

extern "C" void kernel_launch(void* const* d_in, const int* in_sizes, int n_in,
                              void* d_out, int out_size, void* d_ws, size_t ws_size,
                              hipStream_t stream) {
    const float* data = (const float*)d_in[0];
    const float* conv_w = (const float*)d_in[1];
    float* featn = (float*)d_ws;           // 5760*640*4 = 14.1 MB

    conv_norm_pool<<<NIMG, 320, 0, stream>>>(data, conv_w, featn);

    dim3 grid(NQ, WAY, BATCH);
    sim_greedy<<<grid, 128, 0, stream>>>(featn, (float*)d_out);
}

// Round 3
// 314.435 us; speedup vs baseline: 3.2470x; 3.2470x over previous
//
#include <hip/hip_runtime.h>
#include <math.h>

// Problem constants
#define BATCH 8
#define WAY 5
#define NQ 75
#define NSAMP 80
#define NP 9
#define CCH 640
#define KLEN 192
#define NIMG (BATCH*NSAMP*NP)   // 5760
#define AS 200                  // LDS row stride (bf16 elems) for A tiles

typedef short bf16x8 __attribute__((ext_vector_type(8)));
typedef float f32x16 __attribute__((ext_vector_type(16)));

__device__ __forceinline__ void split_bf16(float x, short& hi, short& lo) {
    unsigned xb = __float_as_uint(x);
    hi = (short)(xb >> 16);
    float hf = __uint_as_float(xb & 0xFFFF0000u);
    float r = x - hf;
    lo = (short)(__float_as_uint(r) >> 16);
}

// ---------------------------------------------------------------------------
// Prep: split conv_w (640x192 fp32) into bf16 hi/lo planes (same [c][k] layout)
__global__ __launch_bounds__(256) void prep_w(
    const float* __restrict__ w, short* __restrict__ w_hi, short* __restrict__ w_lo)
{
    int i = blockIdx.x * 256 + threadIdx.x;
    if (i < CCH * KLEN) {
        short h, l;
        split_bf16(w[i], h, l);
        w_hi[i] = h;
        w_lo[i] = l;
    }
}

// ---------------------------------------------------------------------------
// Kernel 1: per block = 4 patch-images. MFMA 32x32x16 bf16 hi/lo-split GEMM
// (M=64 rows = 4 img x 16 positions, N=640 ch, K=192), then per-position
// L2-norm over channels, position-mean (scale absorbed), per-row L2-norm.
// Writes fully-normalized featn [NIMG][640] fp32.
__global__ __launch_bounds__(512, 2) void conv_mfma(
    const float* __restrict__ x,      // [NIMG,3,32,32]
    const short* __restrict__ w_hi,   // [640][192] bf16 bits
    const short* __restrict__ w_lo,
    float* __restrict__ featn)        // [NIMG][640]
{
    __shared__ short Ah[64 * AS];
    __shared__ short Al[64 * AS];
    __shared__ float ssq_part[8][64];
    __shared__ float inv_s[64];
    __shared__ float pooled_s[4 * CCH];
    __shared__ float rn_part[8];
    __shared__ float invc_s[4];

    const int t = threadIdx.x;
    const int blk = blockIdx.x;

    // ---- P1: load 4 images, rearrange to A[row=img*16+pos][k=ci*64+kh*8+kw],
    //          split fp32 -> bf16 hi/lo into LDS
    {
        const float4* xp = (const float4*)(x + (size_t)blk * 4 * 3072);
#pragma unroll
        for (int i = 0; i < 6; i++) {
            int f = t + i * 512;              // 0..3071 float4s
            int img = f / 768;
            int rem = f - img * 768;
            int ci = rem >> 8;
            int rem2 = rem & 255;
            int h = rem2 >> 3;
            int w4 = (rem2 & 7) << 2;
            int s = ((h >> 3) << 2) + (w4 >> 3);
            int k0 = (ci << 6) + ((h & 7) << 3) + (w4 & 7);
            int row = (img << 4) + s;
            float4 v = xp[f];
            short h0, h1, h2, h3, l0, l1, l2, l3;
            split_bf16(v.x, h0, l0);
            split_bf16(v.y, h1, l1);
            split_bf16(v.z, h2, l2);
            split_bf16(v.w, h3, l3);
            *(short4*)&Ah[row * AS + k0] = make_short4(h0, h1, h2, h3);
            *(short4*)&Al[row * AS + k0] = make_short4(l0, l1, l2, l3);
        }
    }
    __syncthreads();

    const int wv = t >> 6;       // wave 0..7
    const int l  = t & 63;
    const int ln = l & 31;       // MFMA row/col lane index
    const int hh = l >> 5;       // k-half
    const int myMt = wv & 1;     // Mt owned for the shared unit (i==2)

    // Work split: wave w owns nt = w and nt = 8+w (both M-tiles),
    // plus nt = 16+(w>>1) for M-tile (w&1) only. Balanced: 180 MFMA/wave.
    f32x16 acc[3][2];
#pragma unroll
    for (int i = 0; i < 3; i++)
#pragma unroll
        for (int m = 0; m < 2; m++)
#pragma unroll
            for (int r = 0; r < 16; r++) acc[i][m][r] = 0.f;

#pragma unroll
    for (int i = 0; i < 3; i++) {
        int nt = (i < 2) ? (wv + (i << 3)) : (16 + (wv >> 1));
        int c = nt * 32 + ln;
        const short* bph = w_hi + c * KLEN + hh * 8;
        const short* bpl = w_lo + c * KLEN + hh * 8;
        bf16x8 bh[12], bl[12];
#pragma unroll
        for (int ks = 0; ks < 12; ks++) {
            bh[ks] = *(const bf16x8*)(bph + ks * 16);
            bl[ks] = *(const bf16x8*)(bpl + ks * 16);
        }
#pragma unroll
        for (int ks = 0; ks < 12; ks++) {
            int ao = ln * AS + ks * 16 + hh * 8;
            if (i < 2 || myMt == 0) {
                bf16x8 a0h = *(const bf16x8*)&Ah[ao];
                bf16x8 a0l = *(const bf16x8*)&Al[ao];
                acc[i][0] = __builtin_amdgcn_mfma_f32_32x32x16_bf16(a0h, bh[ks], acc[i][0], 0, 0, 0);
                acc[i][0] = __builtin_amdgcn_mfma_f32_32x32x16_bf16(a0l, bh[ks], acc[i][0], 0, 0, 0);
                acc[i][0] = __builtin_amdgcn_mfma_f32_32x32x16_bf16(a0h, bl[ks], acc[i][0], 0, 0, 0);
            }
            if (i < 2 || myMt == 1) {
                bf16x8 a1h = *(const bf16x8*)&Ah[ao + 32 * AS];
                bf16x8 a1l = *(const bf16x8*)&Al[ao + 32 * AS];
                acc[i][1] = __builtin_amdgcn_mfma_f32_32x32x16_bf16(a1h, bh[ks], acc[i][1], 0, 0, 0);
                acc[i][1] = __builtin_amdgcn_mfma_f32_32x32x16_bf16(a1l, bh[ks], acc[i][1], 0, 0, 0);
                acc[i][1] = __builtin_amdgcn_mfma_f32_32x32x16_bf16(a1h, bl[ks], acc[i][1], 0, 0, 0);
            }
        }
    }

    // ---- ssq per row (fp32, from registers). C/D layout (32x32):
    // col = ln, row_local = (r&3) + 8*(r>>2) + 4*hh, row = Mt*32 + row_local.
#pragma unroll
    for (int Mt = 0; Mt < 2; Mt++) {
#pragma unroll
        for (int r = 0; r < 16; r++) {
            float v = 0.f;
#pragma unroll
            for (int i = 0; i < 3; i++) { float a = acc[i][Mt][r]; v += a * a; }
            v += __shfl_xor(v, 1);
            v += __shfl_xor(v, 2);
            v += __shfl_xor(v, 4);
            v += __shfl_xor(v, 8);
            v += __shfl_xor(v, 16);
            if (ln == 0) {
                int rl = (r & 3) + ((r >> 2) << 3) + (hh << 2);
                ssq_part[wv][Mt * 32 + rl] = v;
            }
        }
    }
    __syncthreads();
    if (t < 64) {
        float s = 0.f;
#pragma unroll
        for (int w = 0; w < 8; w++) s += ssq_part[w][t];
        inv_s[t] = 1.f / fmaxf(sqrtf(s), 1e-12f);
    }
    __syncthreads();

    // ---- pooled[img][c] = sum_pos inv[row]*C[row][c]  (mean scale absorbed
    //      by the final row-normalization)
#pragma unroll
    for (int i = 0; i < 3; i++) {
        int nt = (i < 2) ? (wv + (i << 3)) : (16 + (wv >> 1));
        int c = nt * 32 + ln;
#pragma unroll
        for (int Mt = 0; Mt < 2; Mt++) {
            float p0 = 0.f, p1 = 0.f;
#pragma unroll
            for (int r = 0; r < 16; r++) {
                int rl = (r & 3) + ((r >> 2) << 3) + (hh << 2);
                float pv = acc[i][Mt][r] * inv_s[Mt * 32 + rl];
                if (r < 8) p0 += pv; else p1 += pv;
            }
            p0 += __shfl_xor(p0, 32);
            p1 += __shfl_xor(p1, 32);
            bool owned = (i < 2) || (Mt == myMt);
            if (owned && hh == 0) {
                pooled_s[(Mt * 2 + 0) * CCH + c] = p0;
                pooled_s[(Mt * 2 + 1) * CCH + c] = p1;
            }
        }
    }
    __syncthreads();

    // ---- per-image row L2-norm + write featn (coalesced)
    {
        int img = wv >> 1;                       // 2 waves per image
        int u = ((wv & 1) << 6) + l;             // 0..127 within image
        float s = 0.f;
#pragma unroll
        for (int j = 0; j < 5; j++) {
            float pv = pooled_s[img * CCH + u + 128 * j];
            s += pv * pv;
        }
        s += __shfl_xor(s, 1);
        s += __shfl_xor(s, 2);
        s += __shfl_xor(s, 4);
        s += __shfl_xor(s, 8);
        s += __shfl_xor(s, 16);
        s += __shfl_xor(s, 32);
        if (l == 0) rn_part[wv] = s;
    }
    __syncthreads();
    if (t < 4)
        invc_s[t] = 1.f / fmaxf(sqrtf(rn_part[2 * t] + rn_part[2 * t + 1]), 1e-12f);
    __syncthreads();
#pragma unroll
    for (int e0 = 0; e0 < 5; e0++) {
        int e = t + e0 * 512;                    // 0..2559
        int im = e / CCH;
        int c2 = e - im * CCH;
        featn[((size_t)blk * 4 + im) * CCH + c2] = pooled_s[e] * invc_s[im];
    }
}

// ---------------------------------------------------------------------------
// Kernel 2: per (b,m,n): 9x9 sim matrix + greedy row/col-deletion.
__global__ __launch_bounds__(256) void sim_greedy(
    const float* __restrict__ featn,
    float* __restrict__ out)                    // [8][75][5]
{
    __shared__ float rows_s[18][644];           // 9 support + 9 query rows
    __shared__ float part_s[81][2];
    __shared__ float sim_s[81];

    const int n = blockIdx.x;
    const int m = blockIdx.y;
    const int b = blockIdx.z;
    const int t = threadIdx.x;

    // load 18 rows (float4-coalesced)
    for (int e = t; e < 18 * 160; e += 256) {
        int r = e / 160;
        int c4 = e - r * 160;
        int g = (r < NP) ? ((b * NSAMP + m) * NP + r)
                         : ((b * NSAMP + WAY + n) * NP + (r - NP));
        *(float4*)&rows_s[r][c4 << 2] = ((const float4*)(featn + (size_t)g * CCH))[c4];
    }
    __syncthreads();

    // 81 dots, each split across 2 threads (320 elems each)
    if (t < 162) {
        int d = t >> 1;
        int half = t & 1;
        int h = d / NP;
        int wq = d - h * NP;
        const float* ph = rows_s[h];
        const float* pq = rows_s[NP + wq];
        float acc = 0.f;
        int base = half * 80;
#pragma unroll 4
        for (int q = 0; q < 80; q++) {
            float4 a = *(const float4*)&ph[(base + q) << 2];
            float4 bb = *(const float4*)&pq[(base + q) << 2];
            acc += a.x * bb.x + a.y * bb.y + a.z * bb.z + a.w * bb.w;
        }
        part_s[d][half] = acc;
    }
    __syncthreads();
    if (t < 81) sim_s[t] = part_s[t][0] + part_s[t][1];
    __syncthreads();

    // wave-parallel greedy (wave 0 only). Lane t owns sim[t] and sim[t+64].
    if (t < 64) {
        float v0 = sim_s[t];
        float v1 = (t < 17) ? sim_s[t + 64] : -3.0e38f;
        int d0r = t / NP, d0c = t - d0r * NP;
        int d1 = t + 64;
        int d1r = d1 / NP, d1c = d1 - d1r * NP;
        unsigned rm = 0x1FF, cm = 0x1FF;
        float total = 0.f, beta = 1.f;
        for (int it = 0; it < NP; it++) {
            float c0 = (((rm >> d0r) & 1u) && ((cm >> d0c) & 1u)) ? v0 : -3.0e38f;
            int i0 = t;
            float c1 = (t < 17 && ((rm >> d1r) & 1u) && ((cm >> d1c) & 1u)) ? v1 : -3.0e38f;
            if (c1 > c0) { c0 = c1; i0 = d1; }
#pragma unroll
            for (int off = 32; off >= 1; off >>= 1) {
                float ov = __shfl_xor(c0, off);
                int oi = __shfl_xor(i0, off);
                if (ov > c0 || (ov == c0 && oi < i0)) { c0 = ov; i0 = oi; }
            }
            total += fmaxf(c0, 0.f) * beta;
            beta *= 0.5f;
            int br = i0 / NP;
            int bc = i0 - br * NP;
            rm &= ~(1u << br);
            cm &= ~(1u << bc);
        }
        if (t == 0) out[((size_t)b * NQ + n) * WAY + m] = total;
    }
}

extern "C" void kernel_launch(void* const* d_in, const int* in_sizes, int n_in,
                              void* d_out, int out_size, void* d_ws, size_t ws_size,
                              hipStream_t stream) {
    const float* data = (const float*)d_in[0];
    const float* conv_w = (const float*)d_in[1];

    float* featn = (float*)d_ws;                           // 14,745,600 B
    short* w_hi = (short*)((char*)d_ws + (size_t)NIMG * CCH * 4);
    short* w_lo = w_hi + CCH * KLEN;                       // +245,760 B each

    prep_w<<<(CCH * KLEN + 255) / 256, 256, 0, stream>>>(conv_w, w_hi, w_lo);
    conv_mfma<<<NIMG / 4, 512, 0, stream>>>(data, w_hi, w_lo, featn);
    dim3 grid(NQ, WAY, BATCH);
    sim_greedy<<<grid, 256, 0, stream>>>(featn, (float*)d_out);
}

// Round 4
// 267.424 us; speedup vs baseline: 3.8178x; 1.1758x over previous
//
#include <hip/hip_runtime.h>
#include <math.h>

// Problem constants
#define BATCH 8
#define WAY 5
#define NQ 75
#define NSAMP 80
#define NP 9
#define CCH 640
#define KLEN 192
#define NIMG (BATCH*NSAMP*NP)   // 5760
#define AS 200                  // LDS row stride (bf16 elems) for A tiles
#define NTILES 20               // 640/32 n-tiles
#define NKS 12                  // 192/16 k-steps
#define NFRAG (NTILES*NKS*64)   // 15360 lane-fragments per plane

typedef short bf16x8 __attribute__((ext_vector_type(8)));
typedef float f32x16 __attribute__((ext_vector_type(16)));

__device__ __forceinline__ void split_bf16(float x, short& hi, short& lo) {
    unsigned xb = __float_as_uint(x);
    hi = (short)(xb >> 16);
    float hf = __uint_as_float(xb & 0xFFFF0000u);
    float r = x - hf;
    lo = (short)(__float_as_uint(r) >> 16);
}

// ---------------------------------------------------------------------------
// Prep: split conv_w (640x192 fp32) into bf16 hi/lo planes, PACKED in MFMA
// B-fragment order: frag f = nt*12+ks, lane l; element j (0..7) is
// w[c = nt*32 + (l&31)][k = ks*16 + (l>>5)*8 + j].
// Wave load in the GEMM becomes one coalesced 16B/lane dwordx4.
__global__ __launch_bounds__(256) void prep_w_pack(
    const float* __restrict__ w, short* __restrict__ w_hi, short* __restrict__ w_lo)
{
    int i = blockIdx.x * 256 + threadIdx.x;   // one lane-fragment per thread
    if (i < NFRAG) {
        int l = i & 63;
        int frag = i >> 6;
        int ks = frag % NKS;
        int nt = frag / NKS;
        int c = nt * 32 + (l & 31);
        int kb = ks * 16 + (l >> 5) * 8;
        const float* src = w + c * KLEN + kb;
        short h[8], lo[8];
#pragma unroll
        for (int j = 0; j < 8; j++) split_bf16(src[j], h[j], lo[j]);
        *(short4*)(w_hi + (size_t)i * 8)     = make_short4(h[0], h[1], h[2], h[3]);
        *(short4*)(w_hi + (size_t)i * 8 + 4) = make_short4(h[4], h[5], h[6], h[7]);
        *(short4*)(w_lo + (size_t)i * 8)     = make_short4(lo[0], lo[1], lo[2], lo[3]);
        *(short4*)(w_lo + (size_t)i * 8 + 4) = make_short4(lo[4], lo[5], lo[6], lo[7]);
    }
}

// ---------------------------------------------------------------------------
// Kernel 1: per block = 4 patch-images. MFMA 32x32x16 bf16 hi/lo-split GEMM
// (M=64 rows = 4 img x 16 positions, N=640 ch, K=192), then per-position
// L2-norm over channels, position-mean (scale absorbed), per-row L2-norm.
__global__ __launch_bounds__(512, 2) void conv_mfma(
    const float* __restrict__ x,      // [NIMG,3,32,32]
    const short* __restrict__ w_hi,   // packed B-fragments, bf16 bits
    const short* __restrict__ w_lo,
    float* __restrict__ featn)        // [NIMG][640]
{
    __shared__ short Ah[64 * AS];
    __shared__ short Al[64 * AS];
    __shared__ float ssq_part[8][64];
    __shared__ float inv_s[64];
    __shared__ float pooled_s[4 * CCH];
    __shared__ float rn_part[8];
    __shared__ float invc_s[4];

    const int t = threadIdx.x;
    const int blk = blockIdx.x;

    // ---- load 4 images, rearrange to A[row=img*16+pos][k], split hi/lo
    {
        const float4* xp = (const float4*)(x + (size_t)blk * 4 * 3072);
#pragma unroll
        for (int i = 0; i < 6; i++) {
            int f = t + i * 512;              // 0..3071 float4s
            int img = f / 768;
            int rem = f - img * 768;
            int ci = rem >> 8;
            int rem2 = rem & 255;
            int h = rem2 >> 3;
            int w4 = (rem2 & 7) << 2;
            int s = ((h >> 3) << 2) + (w4 >> 3);
            int k0 = (ci << 6) + ((h & 7) << 3) + (w4 & 7);
            int row = (img << 4) + s;
            float4 v = xp[f];
            short h0, h1, h2, h3, l0, l1, l2, l3;
            split_bf16(v.x, h0, l0);
            split_bf16(v.y, h1, l1);
            split_bf16(v.z, h2, l2);
            split_bf16(v.w, h3, l3);
            *(short4*)&Ah[row * AS + k0] = make_short4(h0, h1, h2, h3);
            *(short4*)&Al[row * AS + k0] = make_short4(l0, l1, l2, l3);
        }
    }
    __syncthreads();

    const int wv = t >> 6;       // wave 0..7
    const int l  = t & 63;
    const int ln = l & 31;       // MFMA row/col lane index
    const int hh = l >> 5;       // k-half
    const int myMt = wv & 1;     // Mt owned for the shared unit (i==2)

    f32x16 acc[3][2];
#pragma unroll
    for (int i = 0; i < 3; i++)
#pragma unroll
        for (int m = 0; m < 2; m++)
#pragma unroll
            for (int r = 0; r < 16; r++) acc[i][m][r] = 0.f;

#pragma unroll
    for (int i = 0; i < 3; i++) {
        int nt = (i < 2) ? (wv + (i << 3)) : (16 + (wv >> 1));
        const bf16x8* bhp = (const bf16x8*)w_hi + (size_t)(nt * NKS) * 64 + l;
        const bf16x8* blp = (const bf16x8*)w_lo + (size_t)(nt * NKS) * 64 + l;
        bf16x8 bh = bhp[0];
        bf16x8 blo = blp[0];
#pragma unroll
        for (int ks = 0; ks < NKS; ks++) {
            bf16x8 bh_n, bl_n;
            if (ks < NKS - 1) {               // register prefetch of next frag
                bh_n = bhp[(ks + 1) * 64];
                bl_n = blp[(ks + 1) * 64];
            }
            int ao = ln * AS + ks * 16 + hh * 8;
            if (i < 2 || myMt == 0) {
                bf16x8 a0h = *(const bf16x8*)&Ah[ao];
                bf16x8 a0l = *(const bf16x8*)&Al[ao];
                acc[i][0] = __builtin_amdgcn_mfma_f32_32x32x16_bf16(a0h, bh,  acc[i][0], 0, 0, 0);
                acc[i][0] = __builtin_amdgcn_mfma_f32_32x32x16_bf16(a0l, bh,  acc[i][0], 0, 0, 0);
                acc[i][0] = __builtin_amdgcn_mfma_f32_32x32x16_bf16(a0h, blo, acc[i][0], 0, 0, 0);
            }
            if (i < 2 || myMt == 1) {
                bf16x8 a1h = *(const bf16x8*)&Ah[ao + 32 * AS];
                bf16x8 a1l = *(const bf16x8*)&Al[ao + 32 * AS];
                acc[i][1] = __builtin_amdgcn_mfma_f32_32x32x16_bf16(a1h, bh,  acc[i][1], 0, 0, 0);
                acc[i][1] = __builtin_amdgcn_mfma_f32_32x32x16_bf16(a1l, bh,  acc[i][1], 0, 0, 0);
                acc[i][1] = __builtin_amdgcn_mfma_f32_32x32x16_bf16(a1h, blo, acc[i][1], 0, 0, 0);
            }
            bh = bh_n;
            blo = bl_n;
        }
    }

    // ---- ssq per row. C/D layout (32x32): col=ln, row_local=(r&3)+8*(r>>2)+4*hh
#pragma unroll
    for (int Mt = 0; Mt < 2; Mt++) {
#pragma unroll
        for (int r = 0; r < 16; r++) {
            float v = 0.f;
#pragma unroll
            for (int i = 0; i < 3; i++) { float a = acc[i][Mt][r]; v += a * a; }
            v += __shfl_xor(v, 1);
            v += __shfl_xor(v, 2);
            v += __shfl_xor(v, 4);
            v += __shfl_xor(v, 8);
            v += __shfl_xor(v, 16);
            if (ln == 0) {
                int rl = (r & 3) + ((r >> 2) << 3) + (hh << 2);
                ssq_part[wv][Mt * 32 + rl] = v;
            }
        }
    }
    __syncthreads();
    if (t < 64) {
        float s = 0.f;
#pragma unroll
        for (int w = 0; w < 8; w++) s += ssq_part[w][t];
        inv_s[t] = 1.f / fmaxf(sqrtf(s), 1e-12f);
    }
    __syncthreads();

    // ---- pooled[img][c] = sum_pos inv[row]*C[row][c]
#pragma unroll
    for (int i = 0; i < 3; i++) {
        int nt = (i < 2) ? (wv + (i << 3)) : (16 + (wv >> 1));
        int c = nt * 32 + ln;
#pragma unroll
        for (int Mt = 0; Mt < 2; Mt++) {
            float p0 = 0.f, p1 = 0.f;
#pragma unroll
            for (int r = 0; r < 16; r++) {
                int rl = (r & 3) + ((r >> 2) << 3) + (hh << 2);
                float pv = acc[i][Mt][r] * inv_s[Mt * 32 + rl];
                if (r < 8) p0 += pv; else p1 += pv;
            }
            p0 += __shfl_xor(p0, 32);
            p1 += __shfl_xor(p1, 32);
            bool owned = (i < 2) || (Mt == myMt);
            if (owned && hh == 0) {
                pooled_s[(Mt * 2 + 0) * CCH + c] = p0;
                pooled_s[(Mt * 2 + 1) * CCH + c] = p1;
            }
        }
    }
    __syncthreads();

    // ---- per-image row L2-norm + write featn (coalesced)
    {
        int img = wv >> 1;
        int u = ((wv & 1) << 6) + l;
        float s = 0.f;
#pragma unroll
        for (int j = 0; j < 5; j++) {
            float pv = pooled_s[img * CCH + u + 128 * j];
            s += pv * pv;
        }
        s += __shfl_xor(s, 1);
        s += __shfl_xor(s, 2);
        s += __shfl_xor(s, 4);
        s += __shfl_xor(s, 8);
        s += __shfl_xor(s, 16);
        s += __shfl_xor(s, 32);
        if (l == 0) rn_part[wv] = s;
    }
    __syncthreads();
    if (t < 4)
        invc_s[t] = 1.f / fmaxf(sqrtf(rn_part[2 * t] + rn_part[2 * t + 1]), 1e-12f);
    __syncthreads();
#pragma unroll
    for (int e0 = 0; e0 < 5; e0++) {
        int e = t + e0 * 512;
        int im = e / CCH;
        int c2 = e - im * CCH;
        featn[((size_t)blk * 4 + im) * CCH + c2] = pooled_s[e] * invc_s[im];
    }
}

// ---------------------------------------------------------------------------
// Kernel 2: per (b,m,n): 9x9 sim matrix + greedy row/col-deletion.
__global__ __launch_bounds__(256) void sim_greedy(
    const float* __restrict__ featn,
    float* __restrict__ out)                    // [8][75][5]
{
    __shared__ float rows_s[18][644];
    __shared__ float part_s[81][2];
    __shared__ float sim_s[81];

    const int n = blockIdx.x;
    const int m = blockIdx.y;
    const int b = blockIdx.z;
    const int t = threadIdx.x;

    for (int e = t; e < 18 * 160; e += 256) {
        int r = e / 160;
        int c4 = e - r * 160;
        int g = (r < NP) ? ((b * NSAMP + m) * NP + r)
                         : ((b * NSAMP + WAY + n) * NP + (r - NP));
        *(float4*)&rows_s[r][c4 << 2] = ((const float4*)(featn + (size_t)g * CCH))[c4];
    }
    __syncthreads();

    if (t < 162) {
        int d = t >> 1;
        int half = t & 1;
        int h = d / NP;
        int wq = d - h * NP;
        const float* ph = rows_s[h];
        const float* pq = rows_s[NP + wq];
        float acc = 0.f;
        int base = half * 80;
#pragma unroll 4
        for (int q = 0; q < 80; q++) {
            float4 a = *(const float4*)&ph[(base + q) << 2];
            float4 bb = *(const float4*)&pq[(base + q) << 2];
            acc += a.x * bb.x + a.y * bb.y + a.z * bb.z + a.w * bb.w;
        }
        part_s[d][half] = acc;
    }
    __syncthreads();
    if (t < 81) sim_s[t] = part_s[t][0] + part_s[t][1];
    __syncthreads();

    if (t < 64) {
        float v0 = sim_s[t];
        float v1 = (t < 17) ? sim_s[t + 64] : -3.0e38f;
        int d0r = t / NP, d0c = t - d0r * NP;
        int d1 = t + 64;
        int d1r = d1 / NP, d1c = d1 - d1r * NP;
        unsigned rm = 0x1FF, cm = 0x1FF;
        float total = 0.f, beta = 1.f;
        for (int it = 0; it < NP; it++) {
            float c0 = (((rm >> d0r) & 1u) && ((cm >> d0c) & 1u)) ? v0 : -3.0e38f;
            int i0 = t;
            float c1 = (t < 17 && ((rm >> d1r) & 1u) && ((cm >> d1c) & 1u)) ? v1 : -3.0e38f;
            if (c1 > c0) { c0 = c1; i0 = d1; }
#pragma unroll
            for (int off = 32; off >= 1; off >>= 1) {
                float ov = __shfl_xor(c0, off);
                int oi = __shfl_xor(i0, off);
                if (ov > c0 || (ov == c0 && oi < i0)) { c0 = ov; i0 = oi; }
            }
            total += fmaxf(c0, 0.f) * beta;
            beta *= 0.5f;
            int br = i0 / NP;
            int bc = i0 - br * NP;
            rm &= ~(1u << br);
            cm &= ~(1u << bc);
        }
        if (t == 0) out[((size_t)b * NQ + n) * WAY + m] = total;
    }
}

extern "C" void kernel_launch(void* const* d_in, const int* in_sizes, int n_in,
                              void* d_out, int out_size, void* d_ws, size_t ws_size,
                              hipStream_t stream) {
    const float* data = (const float*)d_in[0];
    const float* conv_w = (const float*)d_in[1];

    float* featn = (float*)d_ws;                           // 14,745,600 B
    short* w_hi = (short*)((char*)d_ws + (size_t)NIMG * CCH * 4);
    short* w_lo = w_hi + (size_t)NFRAG * 8;                // +245,760 B each

    prep_w_pack<<<(NFRAG + 255) / 256, 256, 0, stream>>>(conv_w, w_hi, w_lo);
    conv_mfma<<<NIMG / 4, 512, 0, stream>>>(data, w_hi, w_lo, featn);
    dim3 grid(NQ, WAY, BATCH);
    sim_greedy<<<grid, 256, 0, stream>>>(featn, (float*)d_out);
}